// Round 16
// baseline (499.995 us; speedup 1.0000x reference)
//
#include <hip/hip_runtime.h>
#include <math.h>

typedef __bf16 bf16;
typedef __attribute__((ext_vector_type(8))) __bf16 bf16x8;
typedef __attribute__((ext_vector_type(4))) __bf16 bf16x4;
typedef __attribute__((ext_vector_type(4))) float f32x4;

#define AS1 __attribute__((address_space(1)))
#define AS3 __attribute__((address_space(3)))

__device__ __forceinline__ void async16(const void* g, void* l) {
  __builtin_amdgcn_global_load_lds((AS1 void*)g, (AS3 void*)l, 16, 0, 0);
}

__device__ __forceinline__ f32x4 mfma16(bf16x8 a, bf16x8 b, f32x4 c) {
  return __builtin_amdgcn_mfma_f32_16x16x32_bf16(a, b, c, 0, 0, 0);
}

__device__ __forceinline__ float logsig(float z) {
  return fminf(z, 0.f) - __logf(1.f + __expf(-fabsf(z)));
}

static constexpr float SCALE = 0.088388347648318447f;  // 1/sqrt(128)

// ---------------- prep kernels ----------------

__global__ __launch_bounds__(256) void transpose_w(const float* __restrict__ W, bf16* __restrict__ Wt) {
  __shared__ float tl[64][65];
  int n0 = blockIdx.x * 64, k0 = blockIdx.y * 64;
  for (int e = threadIdx.x; e < 4096; e += 256) {
    int i = e >> 6, j = e & 63;
    tl[i][j] = W[(size_t)(k0 + i) * 2048 + n0 + j];
  }
  __syncthreads();
  for (int e = threadIdx.x; e < 4096; e += 256) {
    int i = e >> 6, j = e & 63;
    Wt[(size_t)(n0 + i) * 2048 + k0 + j] = (bf16)tl[j][i];
  }
}

__global__ __launch_bounds__(256) void transpose_w4(const float* __restrict__ W0, const float* __restrict__ W1,
                                                    const float* __restrict__ W2, const float* __restrict__ W3,
                                                    bf16* __restrict__ Wt4) {
  __shared__ float tl[64][65];
  int w = blockIdx.x >> 10;
  const float* W = (w == 0) ? W0 : (w == 1) ? W1 : (w == 2) ? W2 : W3;
  bf16* Wt = Wt4 + (size_t)w * 2048 * 2048;
  int bx = blockIdx.x & 1023;
  int n0 = (bx & 31) * 64, k0 = (bx >> 5) * 64;
  for (int e = threadIdx.x; e < 4096; e += 256) {
    int i = e >> 6, j = e & 63;
    tl[i][j] = W[(size_t)(k0 + i) * 2048 + n0 + j];
  }
  __syncthreads();
  for (int e = threadIdx.x; e < 4096; e += 256) {
    int i = e >> 6, j = e & 63;
    Wt[(size_t)(n0 + i) * 2048 + k0 + j] = (bf16)tl[j][i];
  }
}

__global__ __launch_bounds__(256) void cvt_x(const float* __restrict__ x, bf16* __restrict__ xb, int n) {
  for (size_t i = ((size_t)blockIdx.x * 256 + threadIdx.x) * 4; i < (size_t)n; i += (size_t)gridDim.x * 1024) {
    f32x4 v = *(const f32x4*)&x[i];
    bf16x4 o;
    #pragma unroll
    for (int j = 0; j < 4; ++j) o[j] = (bf16)v[j];
    *(bf16x4*)&xb[i] = o;
  }
}

__global__ __launch_bounds__(256) void cvt_wg1(const float* __restrict__ Wg1, bf16* __restrict__ Wg1t) {
  int k = blockIdx.x * 256 + threadIdx.x;
  #pragma unroll
  for (int j = 0; j < 16; ++j) Wg1t[j * 2048 + k] = (bf16)Wg1[(size_t)k * 16 + j];
}

__global__ __launch_bounds__(256) void xg_mfma(const bf16* __restrict__ xb, const bf16* __restrict__ Wg1t,
                                               float* __restrict__ xg) {
  int wave = threadIdx.x >> 6, lane = threadIdx.x & 63;
  int row0 = blockIdx.x * 64 + wave * 16;
  int rsel = lane & 15, klo = (lane >> 4) * 8;
  f32x4 acc = {0.f, 0.f, 0.f, 0.f};
  #pragma unroll 4
  for (int kt = 0; kt < 2048; kt += 32) {
    bf16x8 a = *(const bf16x8*)&xb[(size_t)(row0 + rsel) * 2048 + kt + klo];
    bf16x8 b = *(const bf16x8*)&Wg1t[rsel * 2048 + kt + klo];
    acc = mfma16(a, b, acc);
  }
  int col = lane & 15, r0 = (lane >> 4) * 4;
  #pragma unroll
  for (int r = 0; r < 4; ++r) xg[(size_t)(row0 + r0 + r) * 16 + col] = acc[r];
}

// ---------------- GEMM 256x256, BK=64, 8 waves ----------------
// 2-way compile-time wave-stagger (r14, confirmed) + B 3-deep pipeline with counted
// vmcnt(4) that never drains to 0 in steady state (r9 structure, retested post-stagger).

__device__ __forceinline__ int swzi(int r, int k0) { return r * 64 + ((((k0 >> 3) ^ r) & 7) << 3) + (k0 & 7); }

__device__ __forceinline__ void stage_half(const bf16* __restrict__ Gp, bf16* lds, int rbase, int kt, int h,
                                           int Kdim, int wave, int lane) {
  #pragma unroll
  for (int ii = 0; ii < 2; ++ii) {
    int i = 2 * h + ii;
    int row = (i * 8 + wave) * 8 + (lane >> 3);
    int gcol = (lane & 7) ^ ((lane >> 3) & 7);
    async16(&Gp[(size_t)(rbase + row) * Kdim + kt + gcol * 8], lds + (i * 8 + wave) * 512);
  }
}

template <int R0>
__device__ __forceinline__ void mfma_phase(f32x4 (&acc)[8][4], const bf16x8 (&AF)[2][2], const bf16x8 (&B0)[4],
                                           const bf16x8 (&B1)[4]) {
  __builtin_amdgcn_sched_barrier(0);
  __builtin_amdgcn_s_setprio(1);
  #pragma unroll
  for (int ks = 0; ks < 2; ++ks)
    #pragma unroll
    for (int i = 0; i < 2; ++i)
      #pragma unroll
      for (int nf = 0; nf < 4; ++nf)
        acc[R0 + i][nf] = mfma16(AF[i][ks], ks ? B1[nf] : B0[nf], acc[R0 + i][nf]);
  __builtin_amdgcn_s_setprio(0);
}

// K-loop, compile-time phase rotation OFF (0 even waves, 4 odd) -> static acc indices.
// A double-buffered (staged at q0 for t+1); B triple-buffered (staged at q1 for t+2).
template <int OFF>
__device__ __forceinline__ void gemm_loop(const bf16* __restrict__ A, const bf16* __restrict__ Bt, bf16* sAb,
                                          bf16* sBb, f32x4 (&acc)[8][4], int mt, int nt, int Kdim, int NT,
                                          int wave, int lane, int wr, int wc, int rsel, int klo) {
  constexpr int P0 = OFF & 7, P1 = (OFF + 2) & 7, P2 = (OFF + 4) & 7, P3 = (OFF + 6) & 7;

  auto rdA = [&](bf16x8 (&dst)[2][2], const bf16* base, int m0) {
    #pragma unroll
    for (int i = 0; i < 2; ++i)
      #pragma unroll
      for (int ks = 0; ks < 2; ++ks)
        dst[i][ks] = *(const bf16x8*)&base[swzi(wr * 128 + (m0 + i) * 16 + rsel, ks * 32 + klo)];
  };
  auto rdB = [&](bf16x8 (&dst)[4], const bf16* base, int ks) {
    #pragma unroll
    for (int nf = 0; nf < 4; ++nf)
      dst[nf] = *(const bf16x8*)&base[swzi(wc * 64 + nf * 16 + rsel, ks * 32 + klo)];
  };

  bf16x8 aP[2][2], aQ[2][2], b0[4], b1[4];
  rdB(b0, sBb, 0);
  rdA(aP, sAb, P0);

  for (int t = 0; t < NT; ++t) {
    const bf16* cA = sAb + (t & 1) * 16384;
    const bf16* cB = sBb + (t % 3) * 16384;
    bool more = (t + 1) < NT;

    // q0: stage A[t+1]; read B-ks1 + rows P1; MFMA rows P0
    if (more) {
      bf16* nAp = sAb + ((t + 1) & 1) * 16384;
      stage_half(A, nAp, mt, (t + 1) * 64, 0, Kdim, wave, lane);
      stage_half(A, nAp, mt, (t + 1) * 64, 1, Kdim, wave, lane);
    }
    rdB(b1, cB, 1);
    rdA(aQ, cA, P1);
    mfma_phase<P0>(acc, aP, b0, b1);

    // q1: stage B[t+2] (two tiles ahead); read rows P2; MFMA rows P1
    if (t + 2 < NT) {
      bf16* nBp = sBb + ((t + 2) % 3) * 16384;
      stage_half(Bt, nBp, nt, (t + 2) * 64, 0, Kdim, wave, lane);
      stage_half(Bt, nBp, nt, (t + 2) * 64, 1, Kdim, wave, lane);
    }
    rdA(aP, cA, P2);
    mfma_phase<P1>(acc, aQ, b0, b1);

    // q2: read rows P3; MFMA rows P2; counted wait (B[t+2] stays in flight) + barrier
    rdA(aQ, cA, P3);
    mfma_phase<P2>(acc, aP, b0, b1);
    if (more) {
      if (t + 2 < NT) {
        asm volatile("s_waitcnt vmcnt(4)" ::: "memory");  // drain A[t+1], B[t+1]; keep B[t+2]
      } else {
        asm volatile("s_waitcnt vmcnt(0)" ::: "memory");
      }
      __builtin_amdgcn_sched_barrier(0);
      __builtin_amdgcn_s_barrier();
      __builtin_amdgcn_sched_barrier(0);
    }

    // q3: MFMA rows P3 ks0; preload next tile's b0/aP; MFMA rows P3 ks1
    __builtin_amdgcn_s_setprio(1);
    #pragma unroll
    for (int i = 0; i < 2; ++i)
      #pragma unroll
      for (int nf = 0; nf < 4; ++nf) acc[P3 + i][nf] = mfma16(aQ[i][0], b0[nf], acc[P3 + i][nf]);
    __builtin_amdgcn_s_setprio(0);
    if (more) {
      rdB(b0, sBb + ((t + 1) % 3) * 16384, 0);
      rdA(aP, sAb + ((t + 1) & 1) * 16384, P0);
    }
    __builtin_amdgcn_sched_barrier(0);
    __builtin_amdgcn_s_setprio(1);
    #pragma unroll
    for (int i = 0; i < 2; ++i)
      #pragma unroll
      for (int nf = 0; nf < 4; ++nf) acc[P3 + i][nf] = mfma16(aQ[i][1], b1[nf], acc[P3 + i][nf]);
    __builtin_amdgcn_s_setprio(0);
  }
}

template <int OUTF32>
__global__ __launch_bounds__(512, 1) void gemm256(const bf16* __restrict__ A, const bf16* __restrict__ Bt,
                                                  void* __restrict__ Cout, int Mdim, int Ndim, int Kdim) {
  __shared__ __align__(16) bf16 sA[2][256 * 64];
  __shared__ __align__(16) bf16 sB[3][256 * 64];

  int tid = threadIdx.x;
  int wave = tid >> 6, lane = tid & 63;
  int wr = wave >> 2, wc = wave & 3;
  int rsel = lane & 15, klo = (lane >> 4) * 8;

  int nwg = gridDim.x;
  int cpx = nwg >> 3;
  int bid = blockIdx.x;
  int swzb = (bid & 7) * cpx + (bid >> 3);
  int nbx = Ndim >> 8;
  int mt = (swzb / nbx) << 8, nt = (swzb % nbx) << 8;

  const int NT = Kdim >> 6;

  // prologue: stage A0, B0, B1; drain A0+B0, leave B1 in flight
  stage_half(A, &sA[0][0], mt, 0, 0, Kdim, wave, lane);
  stage_half(A, &sA[0][0], mt, 0, 1, Kdim, wave, lane);
  stage_half(Bt, &sB[0][0], nt, 0, 0, Kdim, wave, lane);
  stage_half(Bt, &sB[0][0], nt, 0, 1, Kdim, wave, lane);
  if (NT > 1) {
    stage_half(Bt, &sB[1][0], nt, 64, 0, Kdim, wave, lane);
    stage_half(Bt, &sB[1][0], nt, 64, 1, Kdim, wave, lane);
    asm volatile("s_waitcnt vmcnt(4)" ::: "memory");
  } else {
    asm volatile("s_waitcnt vmcnt(0)" ::: "memory");
  }
  __builtin_amdgcn_sched_barrier(0);
  __builtin_amdgcn_s_barrier();
  __builtin_amdgcn_sched_barrier(0);

  f32x4 z4 = {0.f, 0.f, 0.f, 0.f};
  f32x4 acc[8][4];
  #pragma unroll
  for (int i = 0; i < 8; ++i)
    #pragma unroll
    for (int j = 0; j < 4; ++j) acc[i][j] = z4;

  // wave-uniform 2-way stagger; both paths have identical barrier sequences
  if ((wave & 1) == 0)
    gemm_loop<0>(A, Bt, &sA[0][0], &sB[0][0], acc, mt, nt, Kdim, NT, wave, lane, wr, wc, rsel, klo);
  else
    gemm_loop<4>(A, Bt, &sA[0][0], &sB[0][0], acc, mt, nt, Kdim, NT, wave, lane, wr, wc, rsel, klo);

  int col0 = nt + wc * 64 + (lane & 15);
  int row0 = mt + wr * 128 + (lane >> 4) * 4;
  for (int mf = 0; mf < 8; ++mf)
    #pragma unroll
    for (int r = 0; r < 4; ++r) {
      size_t rowb = (size_t)(row0 + mf * 16 + r) * Ndim + col0;
      #pragma unroll
      for (int nf = 0; nf < 4; ++nf) {
        if constexpr (OUTF32 != 0)
          ((float*)Cout)[rowb + nf * 16] = acc[mf][nf][r];
        else
          ((bf16*)Cout)[rowb + nf * 16] = (bf16)acc[mf][nf][r];
      }
    }
}

// ---------------- gate_stage: q/k prefetched at entry; G fused matmul+logsig+cumsum ----

__global__ __launch_bounds__(256, 3) void gate_stage(bf16* __restrict__ qb, bf16* __restrict__ kb,
                                                     const float* __restrict__ xg, const float* __restrict__ Wg2,
                                                     const float* __restrict__ bg2, float* __restrict__ adec,
                                                     float* __restrict__ eg0) {
  __shared__ float G[64][132];
  __shared__ float xgs[1024];
  __shared__ float wg2s[2048];
  __shared__ float bg2s[128];
  int bid = blockIdx.x;
  int c = bid & 63, bh = bid >> 6, h = bh & 15;
  int l0row = (bh >> 4) * 4096 + c * 64;
  int tid = threadIdx.x;

  bf16x8 qv[4], kv[4];
  #pragma unroll
  for (int it = 0; it < 4; ++it) {
    int l = (tid >> 4) + it * 16;
    int d0 = (tid & 15) * 8;
    size_t ro = (size_t)(l0row + l) * 2048 + h * 128 + d0;
    qv[it] = *(const bf16x8*)&qb[ro];
    kv[it] = *(const bf16x8*)&kb[ro];
  }

  for (int e = tid; e < 1024; e += 256) xgs[e] = xg[(size_t)(l0row + (e >> 4)) * 16 + (e & 15)];
  for (int e = tid; e < 2048; e += 256) wg2s[e] = Wg2[(size_t)(e >> 7) * 2048 + h * 128 + (e & 127)];
  if (tid < 128) bg2s[tid] = bg2[h * 128 + tid];
  __syncthreads();

  {
    int d = tid & 127, half = tid >> 7;
    float w[16];
    #pragma unroll
    for (int j = 0; j < 16; ++j) w[j] = wg2s[j * 128 + d];
    float bz = bg2s[d];
    float run = 0.f;
    #pragma unroll 4
    for (int l = 0; l < 32; ++l) {
      int lr = half * 32 + l;
      float z = bz;
      #pragma unroll
      for (int j = 0; j < 16; ++j) z += xgs[lr * 16 + j] * w[j];
      run += logsig(z) * (1.0f / 16.0f);
      G[lr][d] = run;
    }
  }
  __syncthreads();
  {
    int d = tid & 127, half = tid >> 7;
    if (half) {
      float base = G[31][d];
      #pragma unroll 4
      for (int l = 32; l < 64; ++l) G[l][d] += base;
    }
  }
  __syncthreads();

  #pragma unroll
  for (int it = 0; it < 4; ++it) {
    int l = (tid >> 4) + it * 16;
    int d0 = (tid & 15) * 8;
    size_t ro = (size_t)(l0row + l) * 2048 + h * 128 + d0;
    bf16x8 qo, ko;
    #pragma unroll
    for (int i = 0; i < 8; ++i) {
      int d = d0 + i;
      float Gl = G[l][d], Gb = G[0][d];
      qo[i] = (bf16)((float)qv[it][i] * SCALE * __expf(Gl - Gb));
      ko[i] = (bf16)((float)kv[it][i] * __expf(Gb - Gl));
    }
    *(bf16x8*)&qb[ro] = qo;
    *(bf16x8*)&kb[ro] = ko;
  }
  if (tid < 128) {
    float g63 = G[63][tid], g0 = G[0][tid];
    adec[(size_t)bid * 128 + tid] = __expf(g63);
    eg0[(size_t)bid * 128 + tid] = __expf(g0);
  }
}

// ---------------- phase A ----------------

__global__ __launch_bounds__(256, 4) void phaseA(const bf16* __restrict__ kh, const bf16* __restrict__ vb,
                                                 const float* __restrict__ adec, const float* __restrict__ eg0,
                                                 bf16* __restrict__ U) {
  __shared__ __align__(16) bf16 KhT[128][76];
  __shared__ __align__(16) bf16 VT[128][76];
  __shared__ float cscs[128];
  int bid = blockIdx.x;
  int c = bid & 63, bh = bid >> 6, h = bh & 15;
  int l0row = (bh >> 4) * 4096 + c * 64;
  int tid = threadIdx.x;
  if (tid < 128) cscs[tid] = adec[(size_t)bid * 128 + tid] / eg0[(size_t)bid * 128 + tid];

  for (int it = 0; it < 4; ++it) {
    int l = (tid >> 4) + it * 16;
    int d0 = (tid & 15) * 8;
    size_t ro = (size_t)(l0row + l) * 2048 + h * 128 + d0;
    bf16x8 kv = *(const bf16x8*)&kh[ro];
    bf16x8 vv = *(const bf16x8*)&vb[ro];
    #pragma unroll
    for (int i = 0; i < 8; ++i) {
      KhT[d0 + i][l] = kv[i];
      VT[d0 + i][l] = vv[i];
    }
  }
  __syncthreads();

  int wave = tid >> 6, lane = tid & 63;
  int rsel = lane & 15, klo = (lane >> 4) * 8;
  f32x4 z4 = {0.f, 0.f, 0.f, 0.f};
  f32x4 acc[2][8];
  for (int i = 0; i < 2; ++i)
    for (int j = 0; j < 8; ++j) acc[i][j] = z4;
  #pragma unroll
  for (int ks = 0; ks < 2; ++ks) {
    bf16x8 a0 = *(const bf16x8*)&VT[(wave * 2 + 0) * 16 + rsel][ks * 32 + klo];
    bf16x8 a1 = *(const bf16x8*)&VT[(wave * 2 + 1) * 16 + rsel][ks * 32 + klo];
    #pragma unroll
    for (int j = 0; j < 8; ++j) {
      bf16x8 bb = *(const bf16x8*)&KhT[j * 16 + rsel][ks * 32 + klo];
      acc[0][j] = mfma16(a0, bb, acc[0][j]);
      acc[1][j] = mfma16(a1, bb, acc[1][j]);
    }
  }
  size_t ub = (size_t)bid * 16384;
  for (int i = 0; i < 2; ++i)
    for (int j = 0; j < 8; ++j)
      #pragma unroll
      for (int r = 0; r < 4; ++r) {
        int vr = (wave * 2 + i) * 16 + (lane >> 4) * 4 + r;
        int d = j * 16 + (lane & 15);
        U[ub + (size_t)vr * 128 + d] = (bf16)(acc[i][j][r] * cscs[d]);
      }
}

// ---------------- phase B: prefetch depth-2 scan ----------------

__global__ __launch_bounds__(256) void phaseB(bf16* __restrict__ U, const float* __restrict__ adec,
                                              float* __restrict__ Sfin) {
  int bh = blockIdx.x >> 4, vg = blockIdx.x & 15;
  int t = threadIdx.x;
  int v = vg * 8 + (t >> 5);
  int d0 = (t & 31) * 4;
  float S[4] = {0.f, 0.f, 0.f, 0.f};
  size_t base = (size_t)bh * 64 * 16384 + (size_t)v * 128 + d0;
  size_t abase = (size_t)bh * 64 * 128 + d0;
  bf16x4 u0 = *(const bf16x4*)&U[base];
  f32x4 a0 = *(const f32x4*)&adec[abase];
  bf16x4 u1 = *(const bf16x4*)&U[base + 16384];
  f32x4 a1 = *(const f32x4*)&adec[abase + 128];
  for (int c = 0; c < 64; ++c) {
    bf16x4 un = u1;
    f32x4 an = a1;
    if (c + 2 < 64) {
      un = *(const bf16x4*)&U[base + (size_t)(c + 2) * 16384];
      an = *(const f32x4*)&adec[abase + (size_t)(c + 2) * 128];
    }
    bf16x4 sv;
    #pragma unroll
    for (int i = 0; i < 4; ++i) sv[i] = (bf16)S[i];
    *(bf16x4*)&U[base + (size_t)c * 16384] = sv;
    #pragma unroll
    for (int i = 0; i < 4; ++i) S[i] = S[i] * a0[i] + (float)u0[i];
    u0 = u1;
    a0 = a1;
    u1 = un;
    a1 = an;
  }
  #pragma unroll
  for (int i = 0; i < 4; ++i) Sfin[((size_t)bh * 128 + d0 + i) * 128 + v] = S[i];
}

// ---------------- phase C: gb prefetch, vectorized epilogue ----------------

__global__ __launch_bounds__(256, 3) void phaseC(const bf16* __restrict__ qh, const bf16* __restrict__ kh,
                                                 const bf16* __restrict__ vb, const bf16* __restrict__ Sc,
                                                 const float* __restrict__ eg0, const bf16* __restrict__ gb,
                                                 const float* __restrict__ nw, bf16* __restrict__ ob) {
  __shared__ __align__(16) char lds[48896];
  bf16(*Qh)[136] = (bf16(*)[136])(lds);
  bf16(*VT)[76] = (bf16(*)[76])(lds + 17408);
  bf16(*A_lds)[76] = (bf16(*)[76])(lds + 36864);
  float* eG0s = (float*)(lds + 46592);
  float* red = (float*)(lds + 47104);
  float* rsq = (float*)(lds + 48128);
  float* nws = (float*)(lds + 48384);
  float(*o_lds)[133] = (float(*)[133])(lds);

  int bid = blockIdx.x;
  int c = bid & 63, bh = bid >> 6, h = bh & 15;
  int l0row = (bh >> 4) * 4096 + c * 64;
  int tid = threadIdx.x;

  int prow = tid >> 2, pd0 = (tid & 3) * 32;
  bf16x8 gpre[4];
  #pragma unroll
  for (int j = 0; j < 4; ++j)
    gpre[j] = *(const bf16x8*)&gb[(size_t)(l0row + prow) * 2048 + h * 128 + pd0 + j * 8];
  if (tid < 128) nws[tid] = nw[tid];

  for (int it = 0; it < 4; ++it) {
    int e = tid + it * 256;
    int l = e >> 4, d0 = (e & 15) * 8;
    *(bf16x8*)&Qh[l][d0] = *(const bf16x8*)&qh[(size_t)(l0row + l) * 2048 + h * 128 + d0];
  }
  for (int it = 0; it < 4; ++it) {
    int l = (tid >> 4) + it * 16;
    int d0 = (tid & 15) * 8;
    bf16x8 vv = *(const bf16x8*)&vb[(size_t)(l0row + l) * 2048 + h * 128 + d0];
    #pragma unroll
    for (int i = 0; i < 8; ++i) VT[d0 + i][l] = vv[i];
  }
  if (tid < 128) eG0s[tid] = eg0[(size_t)bid * 128 + tid];
  __syncthreads();

  int wave = tid >> 6, lane = tid & 63;
  int rsel = lane & 15, klo = (lane >> 4) * 8;
  f32x4 z4 = {0.f, 0.f, 0.f, 0.f};

  bf16x8 bbk[4];
  #pragma unroll
  for (int ks = 0; ks < 4; ++ks)
    bbk[ks] = *(const bf16x8*)&kh[(size_t)(l0row + wave * 16 + rsel) * 2048 + h * 128 + ks * 32 + klo];
  bf16x8 scr[4][2];
  #pragma unroll
  for (int ks = 0; ks < 4; ++ks)
    #pragma unroll
    for (int j = 0; j < 2; ++j)
      scr[ks][j] =
          *(const bf16x8*)&Sc[(size_t)bid * 16384 + (size_t)((wave * 2 + j) * 16 + rsel) * 128 + ks * 32 + klo];

  f32x4 accA[4];
  for (int i = 0; i < 4; ++i) accA[i] = z4;
  #pragma unroll
  for (int ks = 0; ks < 4; ++ks)
    #pragma unroll
    for (int mf = 0; mf < 4; ++mf) {
      bf16x8 aa = *(const bf16x8*)&Qh[mf * 16 + rsel][ks * 32 + klo];
      accA[mf] = mfma16(aa, bbk[ks], accA[mf]);
    }
  #pragma unroll
  for (int mf = 0; mf < 4; ++mf)
    #pragma unroll
    for (int r = 0; r < 4; ++r) {
      int lrow = mf * 16 + (lane >> 4) * 4 + r;
      int scol = wave * 16 + (lane & 15);
      A_lds[lrow][scol] = (bf16)(scol <= lrow ? accA[mf][r] : 0.0f);
    }

  bf16x8 bs[4][2];
  #pragma unroll
  for (int ks = 0; ks < 4; ++ks)
    #pragma unroll
    for (int j = 0; j < 2; ++j)
      #pragma unroll
      for (int i = 0; i < 8; ++i) bs[ks][j][i] = (bf16)((float)scr[ks][j][i] * eG0s[ks * 32 + klo + i]);

  f32x4 accO[4][2];
  for (int i = 0; i < 4; ++i)
    for (int j = 0; j < 2; ++j) accO[i][j] = z4;
  #pragma unroll
  for (int ks = 0; ks < 4; ++ks)
    #pragma unroll
    for (int mf = 0; mf < 4; ++mf) {
      bf16x8 aa = *(const bf16x8*)&Qh[mf * 16 + rsel][ks * 32 + klo];
      accO[mf][0] = mfma16(aa, bs[ks][0], accO[mf][0]);
      accO[mf][1] = mfma16(aa, bs[ks][1], accO[mf][1]);
    }
  __syncthreads();

  #pragma unroll
  for (int ks = 0; ks < 2; ++ks) {
    bf16x8 b0 = *(const bf16x8*)&VT[(wave * 2 + 0) * 16 + rsel][ks * 32 + klo];
    bf16x8 b1 = *(const bf16x8*)&VT[(wave * 2 + 1) * 16 + rsel][ks * 32 + klo];
    #pragma unroll
    for (int mf = 0; mf < 4; ++mf) {
      bf16x8 aa = *(const bf16x8*)&A_lds[mf * 16 + rsel][ks * 32 + klo];
      accO[mf][0] = mfma16(aa, b0, accO[mf][0]);
      accO[mf][1] = mfma16(aa, b1, accO[mf][1]);
    }
  }
  __syncthreads();

  #pragma unroll
  for (int mf = 0; mf < 4; ++mf)
    #pragma unroll
    for (int j = 0; j < 2; ++j)
      #pragma unroll
      for (int r = 0; r < 4; ++r)
        o_lds[mf * 16 + (lane >> 4) * 4 + r][(wave * 2 + j) * 16 + (lane & 15)] = accO[mf][j][r];
  __syncthreads();

  {
    float ss = 0.f;
    #pragma unroll
    for (int i = 0; i < 32; ++i) {
      float xv = o_lds[prow][pd0 + i];
      ss += xv * xv;
    }
    red[tid] = ss;
  }
  __syncthreads();
  if (tid < 64) {
    float s = red[tid * 4] + red[tid * 4 + 1] + red[tid * 4 + 2] + red[tid * 4 + 3];
    rsq[tid] = rsqrtf(s * (1.0f / 128.0f) + 1e-5f);
  }
  __syncthreads();

  {
    float rs = rsq[prow];
    size_t wb = (size_t)(l0row + prow) * 2048 + h * 128 + pd0;
    #pragma unroll
    for (int j = 0; j < 4; ++j) {
      bf16x8 og;
      #pragma unroll
      for (int i = 0; i < 8; ++i) {
        int d = pd0 + j * 8 + i;
        float ov = o_lds[prow][d] * rs * nws[d];
        float gf = (float)gpre[j][i];
        float sil = gf / (1.0f + __expf(-gf));
        og[i] = (bf16)(ov * sil);
      }
      *(bf16x8*)&ob[wb + j * 8] = og;
    }
  }
}

// ---------------- launch ----------------

extern "C" void kernel_launch(void* const* d_in, const int* in_sizes, int n_in, void* d_out, int out_size,
                              void* d_ws, size_t ws_size, hipStream_t stream) {
  const float* x = (const float*)d_in[0];
  const float* Wq = (const float*)d_in[1];
  const float* Wk = (const float*)d_in[2];
  const float* Wv = (const float*)d_in[3];
  const float* Wg1 = (const float*)d_in[4];
  const float* Wg2 = (const float*)d_in[5];
  const float* bg2 = (const float*)d_in[6];
  const float* Wgate = (const float*)d_in[7];
  const float* nw = (const float*)d_in[8];
  const float* Wo = (const float*)d_in[9];
  float* out1 = (float*)d_out;
  float* out2 = out1 + (size_t)8192 * 2048;

  const size_t XG_B = (size_t)8192 * 16 * 4;
  const size_t WG1_B = (size_t)16 * 2048 * 2;
  const size_t TOK_B = (size_t)8192 * 2048 * 2;
  const size_t VEC_B = (size_t)2048 * 128 * 4;
  const size_t U_B = (size_t)32 * 64 * 16384 * 2;

  char* ws = (char*)d_ws;
  float* xgf = (float*)ws;
  bf16* Wg1t = (bf16*)(ws + XG_B);
  bf16* qb = (bf16*)(ws + XG_B + WG1_B);
  bf16* kbuf = (bf16*)(ws + XG_B + WG1_B + TOK_B);
  bf16* vbuf = (bf16*)(ws + XG_B + WG1_B + 2 * TOK_B);
  bf16* gbuf = (bf16*)(ws + XG_B + WG1_B + 3 * TOK_B);
  float* adecf = (float*)(ws + XG_B + WG1_B + 4 * TOK_B);
  float* eg0f = (float*)(ws + XG_B + WG1_B + 4 * TOK_B + VEC_B);
  char* Ureg = ws + XG_B + WG1_B + 4 * TOK_B + 2 * VEC_B;
  bf16* Ub = (bf16*)Ureg;
  bf16* xb = (bf16*)Ureg;
  bf16* Wt4 = (bf16*)(Ureg + TOK_B);
  bf16* WtO = (bf16*)Ureg;
  const size_t NEED = XG_B + WG1_B + 4 * TOK_B + 2 * VEC_B + U_B;
  if (ws_size < NEED) return;

  dim3 tg(32, 32);

  cvt_x<<<4096, 256, 0, stream>>>(x, xb, 8192 * 2048);
  cvt_wg1<<<8, 256, 0, stream>>>(Wg1, Wg1t);
  xg_mfma<<<128, 256, 0, stream>>>(xb, Wg1t, xgf);

  transpose_w4<<<4096, 256, 0, stream>>>(Wq, Wk, Wv, Wgate, Wt4);

  gemm256<0><<<256, 512, 0, stream>>>(xb, Wt4, qb, 8192, 2048, 2048);
  gemm256<0><<<256, 512, 0, stream>>>(xb, Wt4 + (size_t)2048 * 2048, kbuf, 8192, 2048, 2048);
  gemm256<0><<<256, 512, 0, stream>>>(xb, Wt4 + (size_t)2 * 2048 * 2048, vbuf, 8192, 2048, 2048);
  gemm256<0><<<256, 512, 0, stream>>>(xb, Wt4 + (size_t)3 * 2048 * 2048, gbuf, 8192, 2048, 2048);

  gate_stage<<<2048, 256, 0, stream>>>(qb, kbuf, xgf, Wg2, bg2, adecf, eg0f);
  phaseA<<<2048, 256, 0, stream>>>(kbuf, vbuf, adecf, eg0f, Ub);
  phaseB<<<512, 256, 0, stream>>>(Ub, adecf, out2);
  phaseC<<<2048, 256, 0, stream>>>(qb, kbuf, vbuf, Ub, eg0f, gbuf, nw, qb);

  transpose_w<<<tg, 256, 0, stream>>>(Wo, WtO);
  gemm256<1><<<256, 512, 0, stream>>>(qb, WtO, out1, 8192, 2048, 2048);
}

// Round 17
// 496.863 us; speedup vs baseline: 1.0063x; 1.0063x over previous
//
#include <hip/hip_runtime.h>
#include <math.h>

typedef __bf16 bf16;
typedef __attribute__((ext_vector_type(8))) __bf16 bf16x8;
typedef __attribute__((ext_vector_type(4))) __bf16 bf16x4;
typedef __attribute__((ext_vector_type(4))) float f32x4;

#define AS1 __attribute__((address_space(1)))
#define AS3 __attribute__((address_space(3)))

__device__ __forceinline__ void async16(const void* g, void* l) {
  __builtin_amdgcn_global_load_lds((AS1 void*)g, (AS3 void*)l, 16, 0, 0);
}

__device__ __forceinline__ f32x4 mfma16(bf16x8 a, bf16x8 b, f32x4 c) {
  return __builtin_amdgcn_mfma_f32_16x16x32_bf16(a, b, c, 0, 0, 0);
}

__device__ __forceinline__ float logsig(float z) {
  return fminf(z, 0.f) - __logf(1.f + __expf(-fabsf(z)));
}

static constexpr float SCALE = 0.088388347648318447f;  // 1/sqrt(128)

// ---------------- prep kernels ----------------

__global__ __launch_bounds__(256) void transpose_w(const float* __restrict__ W, bf16* __restrict__ Wt) {
  __shared__ float tl[64][65];
  int n0 = blockIdx.x * 64, k0 = blockIdx.y * 64;
  for (int e = threadIdx.x; e < 4096; e += 256) {
    int i = e >> 6, j = e & 63;
    tl[i][j] = W[(size_t)(k0 + i) * 2048 + n0 + j];
  }
  __syncthreads();
  for (int e = threadIdx.x; e < 4096; e += 256) {
    int i = e >> 6, j = e & 63;
    Wt[(size_t)(n0 + i) * 2048 + k0 + j] = (bf16)tl[j][i];
  }
}

__global__ __launch_bounds__(256) void transpose_w4(const float* __restrict__ W0, const float* __restrict__ W1,
                                                    const float* __restrict__ W2, const float* __restrict__ W3,
                                                    bf16* __restrict__ Wt4) {
  __shared__ float tl[64][65];
  int w = blockIdx.x >> 10;
  const float* W = (w == 0) ? W0 : (w == 1) ? W1 : (w == 2) ? W2 : W3;
  bf16* Wt = Wt4 + (size_t)w * 2048 * 2048;
  int bx = blockIdx.x & 1023;
  int n0 = (bx & 31) * 64, k0 = (bx >> 5) * 64;
  for (int e = threadIdx.x; e < 4096; e += 256) {
    int i = e >> 6, j = e & 63;
    tl[i][j] = W[(size_t)(k0 + i) * 2048 + n0 + j];
  }
  __syncthreads();
  for (int e = threadIdx.x; e < 4096; e += 256) {
    int i = e >> 6, j = e & 63;
    Wt[(size_t)(n0 + i) * 2048 + k0 + j] = (bf16)tl[j][i];
  }
}

__global__ __launch_bounds__(256) void cvt_x(const float* __restrict__ x, bf16* __restrict__ xb, int n) {
  for (size_t i = ((size_t)blockIdx.x * 256 + threadIdx.x) * 4; i < (size_t)n; i += (size_t)gridDim.x * 1024) {
    f32x4 v = *(const f32x4*)&x[i];
    bf16x4 o;
    #pragma unroll
    for (int j = 0; j < 4; ++j) o[j] = (bf16)v[j];
    *(bf16x4*)&xb[i] = o;
  }
}

__global__ __launch_bounds__(256) void cvt_wg1(const float* __restrict__ Wg1, bf16* __restrict__ Wg1t) {
  int k = blockIdx.x * 256 + threadIdx.x;
  #pragma unroll
  for (int j = 0; j < 16; ++j) Wg1t[j * 2048 + k] = (bf16)Wg1[(size_t)k * 16 + j];
}

__global__ __launch_bounds__(256) void xg_mfma(const bf16* __restrict__ xb, const bf16* __restrict__ Wg1t,
                                               float* __restrict__ xg) {
  int wave = threadIdx.x >> 6, lane = threadIdx.x & 63;
  int row0 = blockIdx.x * 64 + wave * 16;
  int rsel = lane & 15, klo = (lane >> 4) * 8;
  f32x4 acc = {0.f, 0.f, 0.f, 0.f};
  #pragma unroll 4
  for (int kt = 0; kt < 2048; kt += 32) {
    bf16x8 a = *(const bf16x8*)&xb[(size_t)(row0 + rsel) * 2048 + kt + klo];
    bf16x8 b = *(const bf16x8*)&Wg1t[rsel * 2048 + kt + klo];
    acc = mfma16(a, b, acc);
  }
  int col = lane & 15, r0 = (lane >> 4) * 4;
  #pragma unroll
  for (int r = 0; r < 4; ++r) xg[(size_t)(row0 + r0 + r) * 16 + col] = acc[r];
}

// ---------------- GEMM 256x256, BK=64, 8 waves; 2-way compile-time wave-staggered phases ----------------
// (round-14 measured-best configuration: 2-deep dbuf, one vmcnt(0)+barrier per tile)

__device__ __forceinline__ int swzi(int r, int k0) { return r * 64 + ((((k0 >> 3) ^ r) & 7) << 3) + (k0 & 7); }

__device__ __forceinline__ void stage_half(const bf16* __restrict__ Gp, bf16* lds, int rbase, int kt, int h,
                                           int Kdim, int wave, int lane) {
  #pragma unroll
  for (int ii = 0; ii < 2; ++ii) {
    int i = 2 * h + ii;
    int row = (i * 8 + wave) * 8 + (lane >> 3);
    int gcol = (lane & 7) ^ ((lane >> 3) & 7);
    async16(&Gp[(size_t)(rbase + row) * Kdim + kt + gcol * 8], lds + (i * 8 + wave) * 512);
  }
}

template <int R0>
__device__ __forceinline__ void mfma_phase(f32x4 (&acc)[8][4], const bf16x8 (&AF)[2][2], const bf16x8 (&B0)[4],
                                           const bf16x8 (&B1)[4]) {
  __builtin_amdgcn_sched_barrier(0);
  __builtin_amdgcn_s_setprio(1);
  #pragma unroll
  for (int ks = 0; ks < 2; ++ks)
    #pragma unroll
    for (int i = 0; i < 2; ++i)
      #pragma unroll
      for (int nf = 0; nf < 4; ++nf)
        acc[R0 + i][nf] = mfma16(AF[i][ks], ks ? B1[nf] : B0[nf], acc[R0 + i][nf]);
  __builtin_amdgcn_s_setprio(0);
}

// K-loop with compile-time phase rotation OFF (0 for even waves, 4 for odd) -> static acc indices.
template <int OFF>
__device__ __forceinline__ void gemm_loop(const bf16* __restrict__ A, const bf16* __restrict__ Bt, bf16* sAb,
                                          bf16* sBb, f32x4 (&acc)[8][4], int mt, int nt, int Kdim, int NT,
                                          int wave, int lane, int wr, int wc, int rsel, int klo) {
  constexpr int P0 = OFF & 7, P1 = (OFF + 2) & 7, P2 = (OFF + 4) & 7, P3 = (OFF + 6) & 7;

  auto rdA = [&](bf16x8 (&dst)[2][2], const bf16* base, int m0) {
    #pragma unroll
    for (int i = 0; i < 2; ++i)
      #pragma unroll
      for (int ks = 0; ks < 2; ++ks)
        dst[i][ks] = *(const bf16x8*)&base[swzi(wr * 128 + (m0 + i) * 16 + rsel, ks * 32 + klo)];
  };
  auto rdB = [&](bf16x8 (&dst)[4], const bf16* base, int ks) {
    #pragma unroll
    for (int nf = 0; nf < 4; ++nf)
      dst[nf] = *(const bf16x8*)&base[swzi(wc * 64 + nf * 16 + rsel, ks * 32 + klo)];
  };

  bf16x8 aP[2][2], aQ[2][2], b0[4], b1[4];
  rdB(b0, sBb, 0);
  rdA(aP, sAb, P0);

  for (int t = 0; t < NT; ++t) {
    const bf16* cA = sAb + (t & 1) * 16384;
    const bf16* cB = sBb + (t & 1) * 16384;
    bf16* nAp = sAb + ((t & 1) ^ 1) * 16384;
    bf16* nBp = sBb + ((t & 1) ^ 1) * 16384;
    bool more = (t + 1) < NT;

    // q0: stage A[t+1]; read B-ks1 + rows P1; MFMA rows P0
    if (more) {
      stage_half(A, nAp, mt, (t + 1) * 64, 0, Kdim, wave, lane);
      stage_half(A, nAp, mt, (t + 1) * 64, 1, Kdim, wave, lane);
    }
    rdB(b1, cB, 1);
    rdA(aQ, cA, P1);
    mfma_phase<P0>(acc, aP, b0, b1);

    // q1: stage B[t+1]; read rows P2; MFMA rows P1
    if (more) {
      stage_half(Bt, nBp, nt, (t + 1) * 64, 0, Kdim, wave, lane);
      stage_half(Bt, nBp, nt, (t + 1) * 64, 1, Kdim, wave, lane);
    }
    rdA(aP, cA, P2);
    mfma_phase<P1>(acc, aQ, b0, b1);

    // q2: read rows P3; MFMA rows P2; single per-tile sync point
    rdA(aQ, cA, P3);
    mfma_phase<P2>(acc, aP, b0, b1);
    if (more) {
      asm volatile("s_waitcnt vmcnt(0)" ::: "memory");
      __builtin_amdgcn_sched_barrier(0);
      __builtin_amdgcn_s_barrier();
      __builtin_amdgcn_sched_barrier(0);
    }

    // q3: MFMA rows P3 ks0; preload next tile's b0/aP; MFMA rows P3 ks1
    __builtin_amdgcn_s_setprio(1);
    #pragma unroll
    for (int i = 0; i < 2; ++i)
      #pragma unroll
      for (int nf = 0; nf < 4; ++nf) acc[P3 + i][nf] = mfma16(aQ[i][0], b0[nf], acc[P3 + i][nf]);
    __builtin_amdgcn_s_setprio(0);
    if (more) {
      rdB(b0, nBp, 0);
      rdA(aP, nAp, P0);
    }
    __builtin_amdgcn_sched_barrier(0);
    __builtin_amdgcn_s_setprio(1);
    #pragma unroll
    for (int i = 0; i < 2; ++i)
      #pragma unroll
      for (int nf = 0; nf < 4; ++nf) acc[P3 + i][nf] = mfma16(aQ[i][1], b1[nf], acc[P3 + i][nf]);
    __builtin_amdgcn_s_setprio(0);
  }
}

template <int OUTF32>
__global__ __launch_bounds__(512, 2) void gemm256(const bf16* __restrict__ A, const bf16* __restrict__ Bt,
                                                  void* __restrict__ Cout, int Mdim, int Ndim, int Kdim) {
  __shared__ __align__(16) bf16 sA[2][256 * 64];
  __shared__ __align__(16) bf16 sB[2][256 * 64];

  int tid = threadIdx.x;
  int wave = tid >> 6, lane = tid & 63;
  int wr = wave >> 2, wc = wave & 3;
  int rsel = lane & 15, klo = (lane >> 4) * 8;

  int nwg = gridDim.x;
  int cpx = nwg >> 3;
  int bid = blockIdx.x;
  int swzb = (bid & 7) * cpx + (bid >> 3);
  int nbx = Ndim >> 8;
  int mt = (swzb / nbx) << 8, nt = (swzb % nbx) << 8;

  const int NT = Kdim >> 6;

  stage_half(A, &sA[0][0], mt, 0, 0, Kdim, wave, lane);
  stage_half(A, &sA[0][0], mt, 0, 1, Kdim, wave, lane);
  stage_half(Bt, &sB[0][0], nt, 0, 0, Kdim, wave, lane);
  stage_half(Bt, &sB[0][0], nt, 0, 1, Kdim, wave, lane);
  asm volatile("s_waitcnt vmcnt(0)" ::: "memory");
  __builtin_amdgcn_sched_barrier(0);
  __builtin_amdgcn_s_barrier();
  __builtin_amdgcn_sched_barrier(0);

  f32x4 z4 = {0.f, 0.f, 0.f, 0.f};
  f32x4 acc[8][4];
  #pragma unroll
  for (int i = 0; i < 8; ++i)
    #pragma unroll
    for (int j = 0; j < 4; ++j) acc[i][j] = z4;

  // wave-uniform branch; both paths have identical barrier sequences
  if ((wave & 1) == 0)
    gemm_loop<0>(A, Bt, &sA[0][0], &sB[0][0], acc, mt, nt, Kdim, NT, wave, lane, wr, wc, rsel, klo);
  else
    gemm_loop<4>(A, Bt, &sA[0][0], &sB[0][0], acc, mt, nt, Kdim, NT, wave, lane, wr, wc, rsel, klo);

  int col0 = nt + wc * 64 + (lane & 15);
  int row0 = mt + wr * 128 + (lane >> 4) * 4;
  for (int mf = 0; mf < 8; ++mf)
    #pragma unroll
    for (int r = 0; r < 4; ++r) {
      size_t rowb = (size_t)(row0 + mf * 16 + r) * Ndim + col0;
      #pragma unroll
      for (int nf = 0; nf < 4; ++nf) {
        if constexpr (OUTF32 != 0)
          ((float*)Cout)[rowb + nf * 16] = acc[mf][nf][r];
        else
          ((bf16*)Cout)[rowb + nf * 16] = (bf16)acc[mf][nf][r];
      }
    }
}

// ---------------- gate_stage: q/k prefetched at entry; G fused matmul+logsig+cumsum ----

__global__ __launch_bounds__(256, 3) void gate_stage(bf16* __restrict__ qb, bf16* __restrict__ kb,
                                                     const float* __restrict__ xg, const float* __restrict__ Wg2,
                                                     const float* __restrict__ bg2, float* __restrict__ adec,
                                                     float* __restrict__ eg0) {
  __shared__ float G[64][132];
  __shared__ float xgs[1024];
  __shared__ float wg2s[2048];
  __shared__ float bg2s[128];
  int bid = blockIdx.x;
  int c = bid & 63, bh = bid >> 6, h = bh & 15;
  int l0row = (bh >> 4) * 4096 + c * 64;
  int tid = threadIdx.x;

  bf16x8 qv[4], kv[4];
  #pragma unroll
  for (int it = 0; it < 4; ++it) {
    int l = (tid >> 4) + it * 16;
    int d0 = (tid & 15) * 8;
    size_t ro = (size_t)(l0row + l) * 2048 + h * 128 + d0;
    qv[it] = *(const bf16x8*)&qb[ro];
    kv[it] = *(const bf16x8*)&kb[ro];
  }

  for (int e = tid; e < 1024; e += 256) xgs[e] = xg[(size_t)(l0row + (e >> 4)) * 16 + (e & 15)];
  for (int e = tid; e < 2048; e += 256) wg2s[e] = Wg2[(size_t)(e >> 7) * 2048 + h * 128 + (e & 127)];
  if (tid < 128) bg2s[tid] = bg2[h * 128 + tid];
  __syncthreads();

  {
    int d = tid & 127, half = tid >> 7;
    float w[16];
    #pragma unroll
    for (int j = 0; j < 16; ++j) w[j] = wg2s[j * 128 + d];
    float bz = bg2s[d];
    float run = 0.f;
    #pragma unroll 4
    for (int l = 0; l < 32; ++l) {
      int lr = half * 32 + l;
      float z = bz;
      #pragma unroll
      for (int j = 0; j < 16; ++j) z += xgs[lr * 16 + j] * w[j];
      run += logsig(z) * (1.0f / 16.0f);
      G[lr][d] = run;
    }
  }
  __syncthreads();
  {
    int d = tid & 127, half = tid >> 7;
    if (half) {
      float base = G[31][d];
      #pragma unroll 4
      for (int l = 32; l < 64; ++l) G[l][d] += base;
    }
  }
  __syncthreads();

  #pragma unroll
  for (int it = 0; it < 4; ++it) {
    int l = (tid >> 4) + it * 16;
    int d0 = (tid & 15) * 8;
    size_t ro = (size_t)(l0row + l) * 2048 + h * 128 + d0;
    bf16x8 qo, ko;
    #pragma unroll
    for (int i = 0; i < 8; ++i) {
      int d = d0 + i;
      float Gl = G[l][d], Gb = G[0][d];
      qo[i] = (bf16)((float)qv[it][i] * SCALE * __expf(Gl - Gb));
      ko[i] = (bf16)((float)kv[it][i] * __expf(Gb - Gl));
    }
    *(bf16x8*)&qb[ro] = qo;
    *(bf16x8*)&kb[ro] = ko;
  }
  if (tid < 128) {
    float g63 = G[63][tid], g0 = G[0][tid];
    adec[(size_t)bid * 128 + tid] = __expf(g63);
    eg0[(size_t)bid * 128 + tid] = __expf(g0);
  }
}

// ---------------- phase A ----------------

__global__ __launch_bounds__(256, 4) void phaseA(const bf16* __restrict__ kh, const bf16* __restrict__ vb,
                                                 const float* __restrict__ adec, const float* __restrict__ eg0,
                                                 bf16* __restrict__ U) {
  __shared__ __align__(16) bf16 KhT[128][76];
  __shared__ __align__(16) bf16 VT[128][76];
  __shared__ float cscs[128];
  int bid = blockIdx.x;
  int c = bid & 63, bh = bid >> 6, h = bh & 15;
  int l0row = (bh >> 4) * 4096 + c * 64;
  int tid = threadIdx.x;
  if (tid < 128) cscs[tid] = adec[(size_t)bid * 128 + tid] / eg0[(size_t)bid * 128 + tid];

  for (int it = 0; it < 4; ++it) {
    int l = (tid >> 4) + it * 16;
    int d0 = (tid & 15) * 8;
    size_t ro = (size_t)(l0row + l) * 2048 + h * 128 + d0;
    bf16x8 kv = *(const bf16x8*)&kh[ro];
    bf16x8 vv = *(const bf16x8*)&vb[ro];
    #pragma unroll
    for (int i = 0; i < 8; ++i) {
      KhT[d0 + i][l] = kv[i];
      VT[d0 + i][l] = vv[i];
    }
  }
  __syncthreads();

  int wave = tid >> 6, lane = tid & 63;
  int rsel = lane & 15, klo = (lane >> 4) * 8;
  f32x4 z4 = {0.f, 0.f, 0.f, 0.f};
  f32x4 acc[2][8];
  for (int i = 0; i < 2; ++i)
    for (int j = 0; j < 8; ++j) acc[i][j] = z4;
  #pragma unroll
  for (int ks = 0; ks < 2; ++ks) {
    bf16x8 a0 = *(const bf16x8*)&VT[(wave * 2 + 0) * 16 + rsel][ks * 32 + klo];
    bf16x8 a1 = *(const bf16x8*)&VT[(wave * 2 + 1) * 16 + rsel][ks * 32 + klo];
    #pragma unroll
    for (int j = 0; j < 8; ++j) {
      bf16x8 bb = *(const bf16x8*)&KhT[j * 16 + rsel][ks * 32 + klo];
      acc[0][j] = mfma16(a0, bb, acc[0][j]);
      acc[1][j] = mfma16(a1, bb, acc[1][j]);
    }
  }
  size_t ub = (size_t)bid * 16384;
  for (int i = 0; i < 2; ++i)
    for (int j = 0; j < 8; ++j)
      #pragma unroll
      for (int r = 0; r < 4; ++r) {
        int vr = (wave * 2 + i) * 16 + (lane >> 4) * 4 + r;
        int d = j * 16 + (lane & 15);
        U[ub + (size_t)vr * 128 + d] = (bf16)(acc[i][j][r] * cscs[d]);
      }
}

// ---------------- phase B: prefetch depth-2 scan ----------------

__global__ __launch_bounds__(256) void phaseB(bf16* __restrict__ U, const float* __restrict__ adec,
                                              float* __restrict__ Sfin) {
  int bh = blockIdx.x >> 4, vg = blockIdx.x & 15;
  int t = threadIdx.x;
  int v = vg * 8 + (t >> 5);
  int d0 = (t & 31) * 4;
  float S[4] = {0.f, 0.f, 0.f, 0.f};
  size_t base = (size_t)bh * 64 * 16384 + (size_t)v * 128 + d0;
  size_t abase = (size_t)bh * 64 * 128 + d0;
  bf16x4 u0 = *(const bf16x4*)&U[base];
  f32x4 a0 = *(const f32x4*)&adec[abase];
  bf16x4 u1 = *(const bf16x4*)&U[base + 16384];
  f32x4 a1 = *(const f32x4*)&adec[abase + 128];
  for (int c = 0; c < 64; ++c) {
    bf16x4 un = u1;
    f32x4 an = a1;
    if (c + 2 < 64) {
      un = *(const bf16x4*)&U[base + (size_t)(c + 2) * 16384];
      an = *(const f32x4*)&adec[abase + (size_t)(c + 2) * 128];
    }
    bf16x4 sv;
    #pragma unroll
    for (int i = 0; i < 4; ++i) sv[i] = (bf16)S[i];
    *(bf16x4*)&U[base + (size_t)c * 16384] = sv;
    #pragma unroll
    for (int i = 0; i < 4; ++i) S[i] = S[i] * a0[i] + (float)u0[i];
    u0 = u1;
    a0 = a1;
    u1 = un;
    a1 = an;
  }
  #pragma unroll
  for (int i = 0; i < 4; ++i) Sfin[((size_t)bh * 128 + d0 + i) * 128 + v] = S[i];
}

// ---------------- phase C: gb prefetch, vectorized epilogue ----------------

__global__ __launch_bounds__(256, 3) void phaseC(const bf16* __restrict__ qh, const bf16* __restrict__ kh,
                                                 const bf16* __restrict__ vb, const bf16* __restrict__ Sc,
                                                 const float* __restrict__ eg0, const bf16* __restrict__ gb,
                                                 const float* __restrict__ nw, bf16* __restrict__ ob) {
  __shared__ __align__(16) char lds[48896];
  bf16(*Qh)[136] = (bf16(*)[136])(lds);
  bf16(*VT)[76] = (bf16(*)[76])(lds + 17408);
  bf16(*A_lds)[76] = (bf16(*)[76])(lds + 36864);
  float* eG0s = (float*)(lds + 46592);
  float* red = (float*)(lds + 47104);
  float* rsq = (float*)(lds + 48128);
  float* nws = (float*)(lds + 48384);
  float(*o_lds)[133] = (float(*)[133])(lds);

  int bid = blockIdx.x;
  int c = bid & 63, bh = bid >> 6, h = bh & 15;
  int l0row = (bh >> 4) * 4096 + c * 64;
  int tid = threadIdx.x;

  int prow = tid >> 2, pd0 = (tid & 3) * 32;
  bf16x8 gpre[4];
  #pragma unroll
  for (int j = 0; j < 4; ++j)
    gpre[j] = *(const bf16x8*)&gb[(size_t)(l0row + prow) * 2048 + h * 128 + pd0 + j * 8];
  if (tid < 128) nws[tid] = nw[tid];

  for (int it = 0; it < 4; ++it) {
    int e = tid + it * 256;
    int l = e >> 4, d0 = (e & 15) * 8;
    *(bf16x8*)&Qh[l][d0] = *(const bf16x8*)&qh[(size_t)(l0row + l) * 2048 + h * 128 + d0];
  }
  for (int it = 0; it < 4; ++it) {
    int l = (tid >> 4) + it * 16;
    int d0 = (tid & 15) * 8;
    bf16x8 vv = *(const bf16x8*)&vb[(size_t)(l0row + l) * 2048 + h * 128 + d0];
    #pragma unroll
    for (int i = 0; i < 8; ++i) VT[d0 + i][l] = vv[i];
  }
  if (tid < 128) eG0s[tid] = eg0[(size_t)bid * 128 + tid];
  __syncthreads();

  int wave = tid >> 6, lane = tid & 63;
  int rsel = lane & 15, klo = (lane >> 4) * 8;
  f32x4 z4 = {0.f, 0.f, 0.f, 0.f};

  bf16x8 bbk[4];
  #pragma unroll
  for (int ks = 0; ks < 4; ++ks)
    bbk[ks] = *(const bf16x8*)&kh[(size_t)(l0row + wave * 16 + rsel) * 2048 + h * 128 + ks * 32 + klo];
  bf16x8 scr[4][2];
  #pragma unroll
  for (int ks = 0; ks < 4; ++ks)
    #pragma unroll
    for (int j = 0; j < 2; ++j)
      scr[ks][j] =
          *(const bf16x8*)&Sc[(size_t)bid * 16384 + (size_t)((wave * 2 + j) * 16 + rsel) * 128 + ks * 32 + klo];

  f32x4 accA[4];
  for (int i = 0; i < 4; ++i) accA[i] = z4;
  #pragma unroll
  for (int ks = 0; ks < 4; ++ks)
    #pragma unroll
    for (int mf = 0; mf < 4; ++mf) {
      bf16x8 aa = *(const bf16x8*)&Qh[mf * 16 + rsel][ks * 32 + klo];
      accA[mf] = mfma16(aa, bbk[ks], accA[mf]);
    }
  #pragma unroll
  for (int mf = 0; mf < 4; ++mf)
    #pragma unroll
    for (int r = 0; r < 4; ++r) {
      int lrow = mf * 16 + (lane >> 4) * 4 + r;
      int scol = wave * 16 + (lane & 15);
      A_lds[lrow][scol] = (bf16)(scol <= lrow ? accA[mf][r] : 0.0f);
    }

  bf16x8 bs[4][2];
  #pragma unroll
  for (int ks = 0; ks < 4; ++ks)
    #pragma unroll
    for (int j = 0; j < 2; ++j)
      #pragma unroll
      for (int i = 0; i < 8; ++i) bs[ks][j][i] = (bf16)((float)scr[ks][j][i] * eG0s[ks * 32 + klo + i]);

  f32x4 accO[4][2];
  for (int i = 0; i < 4; ++i)
    for (int j = 0; j < 2; ++j) accO[i][j] = z4;
  #pragma unroll
  for (int ks = 0; ks < 4; ++ks)
    #pragma unroll
    for (int mf = 0; mf < 4; ++mf) {
      bf16x8 aa = *(const bf16x8*)&Qh[mf * 16 + rsel][ks * 32 + klo];
      accO[mf][0] = mfma16(aa, bs[ks][0], accO[mf][0]);
      accO[mf][1] = mfma16(aa, bs[ks][1], accO[mf][1]);
    }
  __syncthreads();

  #pragma unroll
  for (int ks = 0; ks < 2; ++ks) {
    bf16x8 b0 = *(const bf16x8*)&VT[(wave * 2 + 0) * 16 + rsel][ks * 32 + klo];
    bf16x8 b1 = *(const bf16x8*)&VT[(wave * 2 + 1) * 16 + rsel][ks * 32 + klo];
    #pragma unroll
    for (int mf = 0; mf < 4; ++mf) {
      bf16x8 aa = *(const bf16x8*)&A_lds[mf * 16 + rsel][ks * 32 + klo];
      accO[mf][0] = mfma16(aa, b0, accO[mf][0]);
      accO[mf][1] = mfma16(aa, b1, accO[mf][1]);
    }
  }
  __syncthreads();

  #pragma unroll
  for (int mf = 0; mf < 4; ++mf)
    #pragma unroll
    for (int j = 0; j < 2; ++j)
      #pragma unroll
      for (int r = 0; r < 4; ++r)
        o_lds[mf * 16 + (lane >> 4) * 4 + r][(wave * 2 + j) * 16 + (lane & 15)] = accO[mf][j][r];
  __syncthreads();

  {
    float ss = 0.f;
    #pragma unroll
    for (int i = 0; i < 32; ++i) {
      float xv = o_lds[prow][pd0 + i];
      ss += xv * xv;
    }
    red[tid] = ss;
  }
  __syncthreads();
  if (tid < 64) {
    float s = red[tid * 4] + red[tid * 4 + 1] + red[tid * 4 + 2] + red[tid * 4 + 3];
    rsq[tid] = rsqrtf(s * (1.0f / 128.0f) + 1e-5f);
  }
  __syncthreads();

  {
    float rs = rsq[prow];
    size_t wb = (size_t)(l0row + prow) * 2048 + h * 128 + pd0;
    #pragma unroll
    for (int j = 0; j < 4; ++j) {
      bf16x8 og;
      #pragma unroll
      for (int i = 0; i < 8; ++i) {
        int d = pd0 + j * 8 + i;
        float ov = o_lds[prow][d] * rs * nws[d];
        float gf = (float)gpre[j][i];
        float sil = gf / (1.0f + __expf(-gf));
        og[i] = (bf16)(ov * sil);
      }
      *(bf16x8*)&ob[wb + j * 8] = og;
    }
  }
}

// ---------------- launch ----------------

extern "C" void kernel_launch(void* const* d_in, const int* in_sizes, int n_in, void* d_out, int out_size,
                              void* d_ws, size_t ws_size, hipStream_t stream) {
  const float* x = (const float*)d_in[0];
  const float* Wq = (const float*)d_in[1];
  const float* Wk = (const float*)d_in[2];
  const float* Wv = (const float*)d_in[3];
  const float* Wg1 = (const float*)d_in[4];
  const float* Wg2 = (const float*)d_in[5];
  const float* bg2 = (const float*)d_in[6];
  const float* Wgate = (const float*)d_in[7];
  const float* nw = (const float*)d_in[8];
  const float* Wo = (const float*)d_in[9];
  float* out1 = (float*)d_out;
  float* out2 = out1 + (size_t)8192 * 2048;

  const size_t XG_B = (size_t)8192 * 16 * 4;
  const size_t WG1_B = (size_t)16 * 2048 * 2;
  const size_t TOK_B = (size_t)8192 * 2048 * 2;
  const size_t VEC_B = (size_t)2048 * 128 * 4;
  const size_t U_B = (size_t)32 * 64 * 16384 * 2;

  char* ws = (char*)d_ws;
  float* xgf = (float*)ws;
  bf16* Wg1t = (bf16*)(ws + XG_B);
  bf16* qb = (bf16*)(ws + XG_B + WG1_B);
  bf16* kbuf = (bf16*)(ws + XG_B + WG1_B + TOK_B);
  bf16* vbuf = (bf16*)(ws + XG_B + WG1_B + 2 * TOK_B);
  bf16* gbuf = (bf16*)(ws + XG_B + WG1_B + 3 * TOK_B);
  float* adecf = (float*)(ws + XG_B + WG1_B + 4 * TOK_B);
  float* eg0f = (float*)(ws + XG_B + WG1_B + 4 * TOK_B + VEC_B);
  char* Ureg = ws + XG_B + WG1_B + 4 * TOK_B + 2 * VEC_B;
  bf16* Ub = (bf16*)Ureg;
  bf16* xb = (bf16*)Ureg;
  bf16* Wt4 = (bf16*)(Ureg + TOK_B);
  bf16* WtO = (bf16*)Ureg;
  const size_t NEED = XG_B + WG1_B + 4 * TOK_B + 2 * VEC_B + U_B;
  if (ws_size < NEED) return;

  dim3 tg(32, 32);

  cvt_x<<<4096, 256, 0, stream>>>(x, xb, 8192 * 2048);
  cvt_wg1<<<8, 256, 0, stream>>>(Wg1, Wg1t);
  xg_mfma<<<128, 256, 0, stream>>>(xb, Wg1t, xgf);

  transpose_w4<<<4096, 256, 0, stream>>>(Wq, Wk, Wv, Wgate, Wt4);

  gemm256<0><<<256, 512, 0, stream>>>(xb, Wt4, qb, 8192, 2048, 2048);
  gemm256<0><<<256, 512, 0, stream>>>(xb, Wt4 + (size_t)2048 * 2048, kbuf, 8192, 2048, 2048);
  gemm256<0><<<256, 512, 0, stream>>>(xb, Wt4 + (size_t)2 * 2048 * 2048, vbuf, 8192, 2048, 2048);
  gemm256<0><<<256, 512, 0, stream>>>(xb, Wt4 + (size_t)3 * 2048 * 2048, gbuf, 8192, 2048, 2048);

  gate_stage<<<2048, 256, 0, stream>>>(qb, kbuf, xgf, Wg2, bg2, adecf, eg0f);
  phaseA<<<2048, 256, 0, stream>>>(kbuf, vbuf, adecf, eg0f, Ub);
  phaseB<<<512, 256, 0, stream>>>(Ub, adecf, out2);
  phaseC<<<2048, 256, 0, stream>>>(qb, kbuf, vbuf, Ub, eg0f, gbuf, nw, qb);

  transpose_w<<<tg, 256, 0, stream>>>(Wo, WtO);
  gemm256<1><<<256, 512, 0, stream>>>(qb, WtO, out1, 8192, 2048, 2048);
}